// Round 11
// baseline (252.316 us; speedup 1.0000x reference)
//
#include <hip/hip_runtime.h>
#include <hip/hip_fp16.h>
#include <cstdint>
#include <cstddef>
#include <cstring>

// ---------------- bf16 pack/unpack helpers (RNE) ----------------

__device__ inline unsigned pack_bf16x2(float a, float b) {
    unsigned ua = __float_as_uint(a);
    unsigned ub = __float_as_uint(b);
    ua += 0x7fffu + ((ua >> 16) & 1u);
    ub += 0x7fffu + ((ub >> 16) & 1u);
    return (ua >> 16) | (ub & 0xffff0000u);
}
__device__ inline unsigned short bf16_rne(float v) {
    unsigned u = __float_as_uint(v);
    u += 0x7fffu + ((u >> 16) & 1u);
    return (unsigned short)(u >> 16);
}

// ---------------- fp8 (OCP e4m3fn) pack/unpack ----------------

typedef float fv2 __attribute__((ext_vector_type(2)));

template <bool HI>
__device__ inline fv2 fp8_fv2(unsigned u) {
#if __has_builtin(__builtin_amdgcn_cvt_pk_f32_fp8)
    return __builtin_amdgcn_cvt_pk_f32_fp8((int)u, HI);
#else
    unsigned u2 = HI ? (u >> 16) : (u & 0xffffu);
    unsigned w = (u2 & 0xFFu) | ((u2 & 0xFF00u) << 8);
    unsigned hb = ((w & 0x00800080u) << 8) | ((w & 0x007f007fu) << 7);
    __half2 h2;
    memcpy(&h2, &hb, 4);
    float2 f = __half22float2(h2);
    fv2 r;
    r.x = f.x * 256.0f;
    r.y = f.y * 256.0f;
    return r;
#endif
}

// bf16 pair (packed in a uint) -> fv2  (2 bitops, then packed add on use)
__device__ inline fv2 bfpair(unsigned u) {
    union { unsigned q[2]; fv2 f; } t;
    t.q[0] = u << 16;
    t.q[1] = u & 0xffff0000u;
    return t.f;
}

__device__ inline unsigned f32_to_fp8_byte(float v) {
    unsigned short hb = __half_as_ushort(__float2half(v * 0.00390625f));  // v/256
    unsigned t = hb & 0x7fffu;
    t += 0x3fu + ((t >> 7) & 1u);
    return ((hb >> 8) & 0x80u) | (t >> 7);
}

__device__ inline unsigned char f32_to_fp8_b(float v) {
#if __has_builtin(__builtin_amdgcn_cvt_pk_fp8_f32)
    return (unsigned char)(__builtin_amdgcn_cvt_pk_fp8_f32(v, v, 0, false) & 0xff);
#else
    return (unsigned char)f32_to_fp8_byte(v);
#endif
}

typedef int iv4 __attribute__((ext_vector_type(4)));

#define NPART 8
#define KB    32
#define NPP_MAX 12500
#define EB    2048   // edges per bucket block (8 per thread)
#define COLCAP 2048  // per-block LDS col-index cache (32 nodes, deg avg 16)

// ---------------- CSR build (R6-proven chain, R10-frozen) --------
// R7 lesson: mega-fusion pinned all phases at 1 block/CU -> 2x slower. Keep
// the chain; each phase runs at its own occupancy. Boundaries ~1us each.
//  - R3: col scatter-writes confined to L2-sized windows (no amplification)
//  - R5: never issue per-edge global atomics (coherence-point traffic)
//  - R6: ballot bucket -- zero per-edge atomics, 8 global atomics per block
//  - R10: finalize preloads slice counts into registers; scan folded in.

__global__ __launch_bounds__(256) void k_bucket_ballot(const int* __restrict__ src,
                                                       const int* __restrict__ dst,
                                                       int* __restrict__ cursor8,
                                                       unsigned* __restrict__ pairs,
                                                       int E, int npp, int capE,
                                                       int srcb) {
    __shared__ int sWcnt[4][NPART];
    __shared__ int sWoff[4][NPART];
    int tid = threadIdx.x;
    int wv = tid >> 6;
    int lane = tid & 63;
    int base_e = blockIdx.x * EB + tid * 8;
    int nv = min(8, E - base_e);
    if (nv < 0) nv = 0;
    int dv[8], sv[8];
    if (nv == 8) {
        *(iv4*)(dv + 0) = *(const iv4*)(dst + base_e + 0);
        *(iv4*)(dv + 4) = *(const iv4*)(dst + base_e + 4);
        *(iv4*)(sv + 0) = *(const iv4*)(src + base_e + 0);
        *(iv4*)(sv + 4) = *(const iv4*)(src + base_e + 4);
    } else {
        for (int k = 0; k < 8; ++k) {
            dv[k] = (k < nv) ? dst[base_e + k] : -1;
            sv[k] = (k < nv) ? src[base_e + k] : 0;
        }
    }
    unsigned long long below = (1ull << lane) - 1ull;
    int wb[NPART];
#pragma unroll
    for (int pp = 0; pp < NPART; ++pp) wb[pp] = 0;
    int pv[8], pos[8];
#pragma unroll
    for (int s = 0; s < 8; ++s) {
        int d = dv[s];
        int p = (d >= 0) ? (int)((unsigned)d / (unsigned)npp) : NPART;
        pv[s] = p;
        unsigned long long msel = 0;
        int base = 0;
#pragma unroll
        for (int pp = 0; pp < NPART; ++pp) {
            unsigned long long m = __ballot(p == pp);
            if (p == pp) { msel = m; base = wb[pp]; }
            wb[pp] += (int)__popcll(m);   // ballot result is wave-uniform
        }
        pos[s] = base + (int)__popcll(msel & below);
    }
    // wave totals -> LDS (static indexing to keep wb in registers)
    if (lane < NPART) {
        int v = 0;
#pragma unroll
        for (int pp = 0; pp < NPART; ++pp)
            if (lane == pp) v = wb[pp];
        sWcnt[wv][lane] = v;
    }
    __syncthreads();
    if (tid < NPART) {
        int c0 = sWcnt[0][tid], c1 = sWcnt[1][tid], c2 = sWcnt[2][tid], c3 = sWcnt[3][tid];
        int gb = atomicAdd(&cursor8[tid], c0 + c1 + c2 + c3);  // 8 atomics/block
        sWoff[0][tid] = gb;
        sWoff[1][tid] = gb + c0;
        sWoff[2][tid] = gb + c0 + c1;
        sWoff[3][tid] = gb + c0 + c1 + c2;
    }
    __syncthreads();
#pragma unroll
    for (int s = 0; s < 8; ++s) {
        int p = pv[s];
        if (p < NPART) {
            int off = sWoff[wv][p];
            pairs[(size_t)p * capE + off + pos[s]] =
                ((unsigned)(dv[s] - p * npp) << srcb) | (unsigned)sv[s];
        }
    }
}

__global__ __launch_bounds__(256) void k_count_part(const unsigned* __restrict__ pairs,
                                                    const int* __restrict__ cursor8,
                                                    int* __restrict__ cntarr,
                                                    int npp, int capE, int srcb) {
    __shared__ int h[NPP_MAX];
    int p = blockIdx.x & (NPART - 1);
    int b = blockIdx.x >> 3;
    for (int i = threadIdx.x; i < npp; i += 256) h[i] = 0;
    __syncthreads();
    int sz = cursor8[p];
    int chunk = (sz + KB - 1) / KB;
    int s0 = b * chunk;
    int s1 = min(sz, s0 + chunk);
    const unsigned* seg = pairs + (size_t)p * capE;
    for (int i = s0 + threadIdx.x; i < s1; i += 256)
        atomicAdd(&h[seg[i] >> srcb], 1);
    __syncthreads();
    size_t out = (size_t)(p * KB + b) * npp;
    for (int i = threadIdx.x; i < npp; i += 256) cntarr[out + i] = h[i];
}

// Fused: per-node degree (sum of 32 cntarr slices) -> dinv + block-local scan.
__global__ void k_indeg_scan(const int* __restrict__ cntarr,
                             float* __restrict__ dinv,
                             int* __restrict__ row_ptr,
                             int* __restrict__ partials, int n, int npp) {
    __shared__ int s[256];
    int t = threadIdx.x;
    int node0 = blockIdx.x * 1024 + t * 4;
    int v0 = 0, v1 = 0, v2 = 0, v3 = 0;
    if (((npp & 3) == 0) && (node0 + 3 < n) && (node0 / npp == (node0 + 3) / npp)) {
        int p = node0 / npp;
        int dl = node0 - p * npp;
        size_t base = (size_t)p * KB * npp + dl;
        for (int b = 0; b < KB; ++b) {
            iv4 c = *(const iv4*)(cntarr + base + (size_t)b * npp);
            v0 += c.x; v1 += c.y; v2 += c.z; v3 += c.w;
        }
    } else {
        for (int r = 0; r < 4; ++r) {
            int node = node0 + r;
            if (node < n) {
                int p = node / npp;
                int dl = node - p * npp;
                size_t base = (size_t)p * KB * npp + dl;
                int sum = 0;
                for (int b = 0; b < KB; ++b) sum += cntarr[base + (size_t)b * npp];
                if (r == 0) v0 = sum; else if (r == 1) v1 = sum;
                else if (r == 2) v2 = sum; else v3 = sum;
            }
        }
    }
    if (node0 + 0 < n) dinv[node0 + 0] = rsqrtf((float)v0 + 1.0f);
    if (node0 + 1 < n) dinv[node0 + 1] = rsqrtf((float)v1 + 1.0f);
    if (node0 + 2 < n) dinv[node0 + 2] = rsqrtf((float)v2 + 1.0f);
    if (node0 + 3 < n) dinv[node0 + 3] = rsqrtf((float)v3 + 1.0f);
    int sum = v0 + v1 + v2 + v3;
    s[t] = sum;
    __syncthreads();
    for (int off = 1; off < 256; off <<= 1) {
        int x = (t >= off) ? s[t - off] : 0;
        __syncthreads();
        s[t] += x;
        __syncthreads();
    }
    int excl = s[t] - sum;
    if ((node0 + 0) < n) row_ptr[node0 + 0] = excl;
    if ((node0 + 1) < n) row_ptr[node0 + 1] = excl + v0;
    if ((node0 + 2) < n) row_ptr[node0 + 2] = excl + v0 + v1;
    if ((node0 + 3) < n) row_ptr[node0 + 3] = excl + v0 + v1 + v2;
    if (t == 255) partials[blockIdx.x] = s[255];
}

// Fused (R10): redundant in-block scan of partials + row_ptr fixup +
// per-slice base rewrite with REGISTER-PRELOADED counts.
__global__ void k_finalize_bases(int* __restrict__ row_ptr,
                                 const int* __restrict__ partials,
                                 int* __restrict__ cntarr, int n, int E, int npp) {
    __shared__ int s[256];
    int t = threadIdx.x;
    {   // redundant exclusive scan of partials[0..255] (zero-padded past nscan)
        int v = partials[t];
        s[t] = v;
        __syncthreads();
        for (int off = 1; off < 256; off <<= 1) {
            int x = (t >= off) ? s[t - off] : 0;
            __syncthreads();
            s[t] += x;
            __syncthreads();
        }
        int excl = s[t] - v;
        __syncthreads();
        s[t] = excl;
        __syncthreads();
    }
    int i = blockIdx.x * 256 + t;
    if (i >= n) return;
    int rp = row_ptr[i] + s[i >> 10];
    row_ptr[i] = rp;
    if (i == 0) row_ptr[n] = E;
    int p = (unsigned)i / (unsigned)npp;
    int dl = i - p * npp;
    size_t base = (size_t)p * KB * npp + dl;
    int c[KB];
#pragma unroll
    for (int b = 0; b < KB; ++b) c[b] = cntarr[base + (size_t)b * npp];
    int run = rp;
#pragma unroll
    for (int b = 0; b < KB; ++b) {
        cntarr[base + (size_t)b * npp] = run;
        run += c[b];
    }
}

__global__ __launch_bounds__(256) void k_fill2(const unsigned* __restrict__ pairs,
                                               const int* __restrict__ cursor8,
                                               const int* __restrict__ cntarr,
                                               int* __restrict__ col,
                                               int npp, int capE, int srcb) {
    __shared__ int cur[NPP_MAX];
    int p = blockIdx.x & (NPART - 1);
    int b = blockIdx.x >> 3;
    size_t slice = (size_t)(p * KB + b) * npp;
    for (int i = threadIdx.x; i < npp; i += 256) cur[i] = cntarr[slice + i];
    __syncthreads();
    int sz = cursor8[p];
    int chunk = (sz + KB - 1) / KB;
    int s0 = b * chunk;
    int s1 = min(sz, s0 + chunk);
    const unsigned* seg = pairs + (size_t)p * capE;
    unsigned smask = (1u << srcb) - 1u;
    for (int i = s0 + threadIdx.x; i < s1; i += 256) {
        unsigned u = seg[i];
        int pos = atomicAdd(&cur[u >> srcb], 1);
        col[pos] = (int)(u & smask);
    }
}

// ---------------- MFMA GEMMs ----------------
typedef __attribute__((ext_vector_type(8))) short short8;
typedef __attribute__((ext_vector_type(4))) float f32x4;

union FragU {
    short8 s;
    uint4 u4;
    unsigned u[4];
};

__device__ inline void packW_body(const float* __restrict__ W, unsigned* __restrict__ Bp,
                                  int NOUT, int NT) {
    int nf = 4 * NT * 64;
    for (int fid = threadIdx.x; fid < nf; fid += 256) {
        int q = fid / (NT * 64);
        int rem = fid - q * NT * 64;
        int nt = rem >> 6;
        int lane = rem & 63;
        int k0 = q * 32 + (lane >> 4) * 8;
        int ncol = nt * 16 + (lane & 15);
        unsigned u[4];
        for (int h = 0; h < 4; ++h) {
            float a = W[(k0 + 2 * h) * NOUT + ncol];
            float b = W[(k0 + 2 * h + 1) * NOUT + ncol];
            u[h] = pack_bf16x2(a, b);
        }
        uint4 o = {u[0], u[1], u[2], u[3]};
        *(uint4*)(Bp + (size_t)fid * 4) = o;
    }
}

// both weight packs in one dispatch; block 0 also zeroes cursor8 + partials
__global__ void k_packW2(const float* __restrict__ W1, unsigned* __restrict__ Bp1,
                         const float* __restrict__ W2, unsigned* __restrict__ Bp2,
                         int* __restrict__ cursor8, int* __restrict__ partials) {
    if (blockIdx.x == 0) {
        if (threadIdx.x < 8) cursor8[threadIdx.x] = 0;
        partials[threadIdx.x] = 0;
        packW_body(W1, Bp1, 128, 8);
    } else {
        packW_body(W2, Bp2, 64, 4);
    }
}

__global__ __launch_bounds__(256) void k_gemm128_mfma(const float* __restrict__ X,
                                                      const unsigned* __restrict__ Bp,
                                                      const float* __restrict__ dinv,
                                                      unsigned char* __restrict__ H8,
                                                      int n) {
    int w = threadIdx.x >> 6;
    int lane = threadIdx.x & 63;
    int quad = lane >> 4;
    int lrow = lane & 15;
    int row0 = blockIdx.x * 64 + w * 16;
    int rowA = min(row0 + lrow, n - 1);

    f32x4 acc[8];
    for (int nt = 0; nt < 8; ++nt) acc[nt] = (f32x4){0.f, 0.f, 0.f, 0.f};

    for (int q = 0; q < 4; ++q) {
        const float* xp = X + (size_t)rowA * 128 + q * 32 + quad * 8;
        float4 x0 = *(const float4*)xp;
        float4 x1 = *(const float4*)(xp + 4);
        FragU a;
        a.u[0] = pack_bf16x2(x0.x, x0.y);
        a.u[1] = pack_bf16x2(x0.z, x0.w);
        a.u[2] = pack_bf16x2(x1.x, x1.y);
        a.u[3] = pack_bf16x2(x1.z, x1.w);
        for (int nt = 0; nt < 8; ++nt) {
            FragU b;
            b.u4 = *(const uint4*)(Bp + ((size_t)(q * 8 + nt) * 64 + lane) * 4);
            acc[nt] = __builtin_amdgcn_mfma_f32_16x16x32_bf16(a.s, b.s, acc[nt], 0, 0, 0);
        }
    }

    int rbase = row0 + quad * 4;
    float dv[4];
    if (rbase + 3 < n) {
        float4 d4 = *(const float4*)(dinv + rbase);
        dv[0] = d4.x; dv[1] = d4.y; dv[2] = d4.z; dv[3] = d4.w;
    } else {
        for (int r = 0; r < 4; ++r) dv[r] = dinv[min(rbase + r, n - 1)];
    }
    for (int nt = 0; nt < 8; ++nt) {
        for (int r = 0; r < 4; ++r) {
            int row = rbase + r;
            if (row < n)
                H8[(size_t)row * 128 + nt * 16 + lrow] = f32_to_fp8_b(dv[r] * acc[nt][r]);
        }
    }
}

// ---------------- Layer-1 aggregation FUSED with the W2 GEMM ----------------
// R11 restructure: OCTET gathering. An 8-lane octet owns one node; lane l
// owns bytes 16l..16l+15 of the 128 B row (uint4 loads). vs quarters @8B:
// one VMEM instruction now serves 8 rows (was 4), bytes-in-flight per wave
// doubles (8-deep unroll = 128 B/lane outstanding), addr VALU per byte
// halves. 32 nodes/block; per-edge unpack math bit-identical.
#define ACC16(u) \
    a0 += fp8_fv2<false>((u).x); a1 += fp8_fv2<true>((u).x); \
    a2 += fp8_fv2<false>((u).y); a3 += fp8_fv2<true>((u).y); \
    a4 += fp8_fv2<false>((u).z); a5 += fp8_fv2<true>((u).z); \
    a6 += fp8_fv2<false>((u).w); a7 += fp8_fv2<true>((u).w);

__global__ __launch_bounds__(256) void k_agg_relu_gemm(const unsigned* __restrict__ hs,
                                                       const float* __restrict__ dinv,
                                                       const int* __restrict__ row_ptr,
                                                       const int* __restrict__ col,
                                                       const float* __restrict__ bias,
                                                       const unsigned* __restrict__ Bp2,
                                                       unsigned short* __restrict__ H16,
                                                       int n) {
    __shared__ unsigned s_a[32][68];
    __shared__ int s_rp[33];
    __shared__ int s_col[COLCAP];
    int tid = threadIdx.x;
    int oct = tid >> 3;                 // local node 0..31
    int node0 = blockIdx.x * 32;
    int node = node0 + oct;
    int l = tid & 7;                    // owns uint4 l of the row (16 B)
    bool alive = node < n;
    int nodeC = alive ? node : (n - 1);
    if (tid < 33) s_rp[tid] = row_ptr[min(node0 + tid, n)];
    __syncthreads();
    int base = s_rp[0];
    int total = s_rp[32] - base;
    int nld = min(total, COLCAP);
    for (int i = tid; i < nld; i += 256) s_col[i] = col[base + i];
    __syncthreads();

    const uint4* hrow = (const uint4*)hs;   // row = 8 uint4 (128 B)
    fv2 a0 = {0.f, 0.f}, a1 = {0.f, 0.f}, a2 = {0.f, 0.f}, a3 = {0.f, 0.f};
    fv2 a4 = {0.f, 0.f}, a5 = {0.f, 0.f}, a6 = {0.f, 0.f}, a7 = {0.f, 0.f};
    if (alive) {   // self term
        uint4 u = hrow[(size_t)node * 8 + l];
        ACC16(u)
    }
    int kk = s_rp[oct] - base;
    int kend = s_rp[oct + 1] - base;
    if (kend <= COLCAP) {   // fast path: indices from LDS (broadcast reads)
        for (; kk + 8 <= kend; kk += 8) {   // 8 edges, 8 uint4 loads in flight
            int cA = s_col[kk + 0], cB = s_col[kk + 1], cC = s_col[kk + 2], cD = s_col[kk + 3];
            int cE = s_col[kk + 4], cF = s_col[kk + 5], cG = s_col[kk + 6], cH = s_col[kk + 7];
            uint4 uA = hrow[(size_t)cA * 8 + l];
            uint4 uB = hrow[(size_t)cB * 8 + l];
            uint4 uC = hrow[(size_t)cC * 8 + l];
            uint4 uD = hrow[(size_t)cD * 8 + l];
            uint4 uE = hrow[(size_t)cE * 8 + l];
            uint4 uF = hrow[(size_t)cF * 8 + l];
            uint4 uG = hrow[(size_t)cG * 8 + l];
            uint4 uH = hrow[(size_t)cH * 8 + l];
            ACC16(uA) ACC16(uB) ACC16(uC) ACC16(uD)
            ACC16(uE) ACC16(uF) ACC16(uG) ACC16(uH)
        }
        for (; kk + 4 <= kend; kk += 4) {
            int cA = s_col[kk + 0], cB = s_col[kk + 1], cC = s_col[kk + 2], cD = s_col[kk + 3];
            uint4 uA = hrow[(size_t)cA * 8 + l];
            uint4 uB = hrow[(size_t)cB * 8 + l];
            uint4 uC = hrow[(size_t)cC * 8 + l];
            uint4 uD = hrow[(size_t)cD * 8 + l];
            ACC16(uA) ACC16(uB) ACC16(uC) ACC16(uD)
        }
        for (; kk < kend; ++kk) {
            uint4 u = hrow[(size_t)s_col[kk] * 8 + l];
            ACC16(u)
        }
    } else {                 // rare fallback: global col
        const int* cp = col + base;
        for (; kk + 4 <= kend; kk += 4) {
            int cA = cp[kk + 0], cB = cp[kk + 1], cC = cp[kk + 2], cD = cp[kk + 3];
            uint4 uA = hrow[(size_t)cA * 8 + l];
            uint4 uB = hrow[(size_t)cB * 8 + l];
            uint4 uC = hrow[(size_t)cC * 8 + l];
            uint4 uD = hrow[(size_t)cD * 8 + l];
            ACC16(uA) ACC16(uB) ACC16(uC) ACC16(uD)
        }
        for (; kk < kend; ++kk) {
            uint4 u = hrow[(size_t)cp[kk] * 8 + l];
            ACC16(u)
        }
    }
    // epilogue: lane finalizes its 16 columns (cols 16l..16l+15) -> LDS tile
    {
        float di = dinv[nodeC];
        const float* bp = bias + 16 * l;
        float4 b0 = *(const float4*)(bp + 0);
        float4 b1 = *(const float4*)(bp + 4);
        float4 b2 = *(const float4*)(bp + 8);
        float4 b3 = *(const float4*)(bp + 12);
        float v0  = fmaf(di, a0.x, b0.x);
        float v1  = fmaf(di, a0.y, b0.y);
        float v2  = fmaf(di, a1.x, b0.z);
        float v3  = fmaf(di, a1.y, b0.w);
        float v4  = fmaf(di, a2.x, b1.x);
        float v5  = fmaf(di, a2.y, b1.y);
        float v6  = fmaf(di, a3.x, b1.z);
        float v7  = fmaf(di, a3.y, b1.w);
        float v8  = fmaf(di, a4.x, b2.x);
        float v9  = fmaf(di, a4.y, b2.y);
        float v10 = fmaf(di, a5.x, b2.z);
        float v11 = fmaf(di, a5.y, b2.w);
        float v12 = fmaf(di, a6.x, b3.x);
        float v13 = fmaf(di, a6.y, b3.y);
        float v14 = fmaf(di, a7.x, b3.z);
        float v15 = fmaf(di, a7.y, b3.w);
        v0  = v0  > 0.f ? v0  : 0.f;  v1  = v1  > 0.f ? v1  : 0.f;
        v2  = v2  > 0.f ? v2  : 0.f;  v3  = v3  > 0.f ? v3  : 0.f;
        v4  = v4  > 0.f ? v4  : 0.f;  v5  = v5  > 0.f ? v5  : 0.f;
        v6  = v6  > 0.f ? v6  : 0.f;  v7  = v7  > 0.f ? v7  : 0.f;
        v8  = v8  > 0.f ? v8  : 0.f;  v9  = v9  > 0.f ? v9  : 0.f;
        v10 = v10 > 0.f ? v10 : 0.f;  v11 = v11 > 0.f ? v11 : 0.f;
        v12 = v12 > 0.f ? v12 : 0.f;  v13 = v13 > 0.f ? v13 : 0.f;
        v14 = v14 > 0.f ? v14 : 0.f;  v15 = v15 > 0.f ? v15 : 0.f;
        uint4 o0 = {pack_bf16x2(v0, v1),   pack_bf16x2(v2, v3),
                    pack_bf16x2(v4, v5),   pack_bf16x2(v6, v7)};
        uint4 o1 = {pack_bf16x2(v8, v9),   pack_bf16x2(v10, v11),
                    pack_bf16x2(v12, v13), pack_bf16x2(v14, v15)};
        *(uint4*)&s_a[oct][8 * l + 0] = o0;
        *(uint4*)&s_a[oct][8 * l + 4] = o1;
    }
    __syncthreads();
    // W2 GEMM: 32 nodes x 128 @ 128 x 64. Wave w owns N-tile w (16 cols),
    // two 16-row tiles. Fragment layouts identical to the standalone gemm64.
    {
        int lane = threadIdx.x & 63;
        int w = threadIdx.x >> 6;
        int quad = lane >> 4;
        int lrow = lane & 15;
        for (int rt = 0; rt < 2; ++rt) {
            f32x4 acc = (f32x4){0.f, 0.f, 0.f, 0.f};
            for (int q = 0; q < 4; ++q) {
                FragU a, b;
                a.u4 = *(const uint4*)&s_a[rt * 16 + lrow][16 * q + 4 * quad];
                b.u4 = *(const uint4*)(Bp2 + ((size_t)(q * 4 + w) * 64 + lane) * 4);
                acc = __builtin_amdgcn_mfma_f32_16x16x32_bf16(a.s, b.s, acc, 0, 0, 0);
            }
            int rbase = node0 + rt * 16 + quad * 4;
            for (int r = 0; r < 4; ++r) {
                int nd = rbase + r;
                if (nd < n)
                    H16[(size_t)nd * 64 + w * 16 + lrow] = bf16_rne(dinv[nd] * acc[r]);
            }
        }
    }
}

// Layer 2: hs rows = 128 B (64 bf16) = 8 uint4. Octet per node; lane owns
// bf16 cols 8l..8l+7 (one uint4). Fused log_softmax (xor 1,2,4 in-octet).
#define ACCL16(u) \
    aA += bfpair((u).x); aB += bfpair((u).y); \
    aC += bfpair((u).z); aD += bfpair((u).w);

__global__ __launch_bounds__(256) void k_agg_lsm(const unsigned* __restrict__ hs,
                                                 const float* __restrict__ dinv,
                                                 const int* __restrict__ row_ptr,
                                                 const int* __restrict__ col,
                                                 const float* __restrict__ bias,
                                                 float* __restrict__ out, int n) {
    __shared__ int s_rp[33];
    __shared__ int s_col[COLCAP];
    int tid = threadIdx.x;
    int oct = tid >> 3;
    int node0 = blockIdx.x * 32;
    int node = node0 + oct;
    int l = tid & 7;
    bool alive = node < n;
    int nodeC = alive ? node : (n - 1);
    if (tid < 33) s_rp[tid] = row_ptr[min(node0 + tid, n)];
    __syncthreads();
    int base = s_rp[0];
    int total = s_rp[32] - base;
    int nld = min(total, COLCAP);
    for (int i = tid; i < nld; i += 256) s_col[i] = col[base + i];
    __syncthreads();

    const uint4* hrow = (const uint4*)hs;   // row = 8 uint4 (128 B)
    fv2 aA = {0.f, 0.f}, aB = {0.f, 0.f}, aC = {0.f, 0.f}, aD = {0.f, 0.f};
    if (alive) {   // self term
        uint4 u = hrow[(size_t)node * 8 + l];
        ACCL16(u)
    }
    int kk = s_rp[oct] - base;
    int kend = s_rp[oct + 1] - base;
    if (kend <= COLCAP) {
        for (; kk + 8 <= kend; kk += 8) {
            int cA = s_col[kk + 0], cB = s_col[kk + 1], cC = s_col[kk + 2], cD = s_col[kk + 3];
            int cE = s_col[kk + 4], cF = s_col[kk + 5], cG = s_col[kk + 6], cH = s_col[kk + 7];
            uint4 uA = hrow[(size_t)cA * 8 + l];
            uint4 uB = hrow[(size_t)cB * 8 + l];
            uint4 uC = hrow[(size_t)cC * 8 + l];
            uint4 uD = hrow[(size_t)cD * 8 + l];
            uint4 uE = hrow[(size_t)cE * 8 + l];
            uint4 uF = hrow[(size_t)cF * 8 + l];
            uint4 uG = hrow[(size_t)cG * 8 + l];
            uint4 uH = hrow[(size_t)cH * 8 + l];
            ACCL16(uA) ACCL16(uB) ACCL16(uC) ACCL16(uD)
            ACCL16(uE) ACCL16(uF) ACCL16(uG) ACCL16(uH)
        }
        for (; kk + 4 <= kend; kk += 4) {
            int cA = s_col[kk + 0], cB = s_col[kk + 1], cC = s_col[kk + 2], cD = s_col[kk + 3];
            uint4 uA = hrow[(size_t)cA * 8 + l];
            uint4 uB = hrow[(size_t)cB * 8 + l];
            uint4 uC = hrow[(size_t)cC * 8 + l];
            uint4 uD = hrow[(size_t)cD * 8 + l];
            ACCL16(uA) ACCL16(uB) ACCL16(uC) ACCL16(uD)
        }
        for (; kk < kend; ++kk) {
            uint4 u = hrow[(size_t)s_col[kk] * 8 + l];
            ACCL16(u)
        }
    } else {
        const int* cp = col + base;
        for (; kk + 4 <= kend; kk += 4) {
            int cA = cp[kk + 0], cB = cp[kk + 1], cC = cp[kk + 2], cD = cp[kk + 3];
            uint4 uA = hrow[(size_t)cA * 8 + l];
            uint4 uB = hrow[(size_t)cB * 8 + l];
            uint4 uC = hrow[(size_t)cC * 8 + l];
            uint4 uD = hrow[(size_t)cD * 8 + l];
            ACCL16(uA) ACCL16(uB) ACCL16(uC) ACCL16(uD)
        }
        for (; kk < kend; ++kk) {
            uint4 u = hrow[(size_t)cp[kk] * 8 + l];
            ACCL16(u)
        }
    }
    float di = dinv[nodeC];
    const float* bp = bias + 8 * l;
    float4 b0 = *(const float4*)(bp + 0);
    float4 b1 = *(const float4*)(bp + 4);
    float v0 = fmaf(di, aA.x, b0.x);
    float v1 = fmaf(di, aA.y, b0.y);
    float v2 = fmaf(di, aB.x, b0.z);
    float v3 = fmaf(di, aB.y, b0.w);
    float v4 = fmaf(di, aC.x, b1.x);
    float v5 = fmaf(di, aC.y, b1.y);
    float v6 = fmaf(di, aD.x, b1.z);
    float v7 = fmaf(di, aD.y, b1.w);
    float m = fmaxf(fmaxf(fmaxf(v0, v1), fmaxf(v2, v3)),
                    fmaxf(fmaxf(v4, v5), fmaxf(v6, v7)));
    for (int off = 4; off; off >>= 1) m = fmaxf(m, __shfl_xor(m, off));
    float s = (__expf(v0 - m) + __expf(v1 - m)) + (__expf(v2 - m) + __expf(v3 - m)) +
              (__expf(v4 - m) + __expf(v5 - m)) + (__expf(v6 - m) + __expf(v7 - m));
    for (int off = 4; off; off >>= 1) s += __shfl_xor(s, off);
    float ls = __logf(s);
    if (alive) {
        float4 o0 = {v0 - m - ls, v1 - m - ls, v2 - m - ls, v3 - m - ls};
        float4 o1 = {v4 - m - ls, v5 - m - ls, v6 - m - ls, v7 - m - ls};
        float* op = out + (size_t)node * 64 + 8 * l;
        *(float4*)(op + 0) = o0;
        *(float4*)(op + 4) = o1;
    }
}

// ---------------- launcher ----------------

extern "C" void kernel_launch(void* const* d_in, const int* in_sizes, int n_in,
                              void* d_out, int out_size, void* d_ws, size_t ws_size,
                              hipStream_t stream) {
    const float* x  = (const float*)d_in[0];
    const int*   ei = (const int*)d_in[1];
    const float* W1 = (const float*)d_in[2];
    const float* b1 = (const float*)d_in[3];
    const float* W2 = (const float*)d_in[4];
    const float* b2 = (const float*)d_in[5];
    float* out = (float*)d_out;

    const int N = in_sizes[0] / 128;   // 100000
    const int E = in_sizes[1] / 2;     // 1600000
    const int* src = ei;
    const int* dst = ei + E;
    const int npp = (N + NPART - 1) / NPART;           // 12500
    const int capE = (E + NPART - 1) / NPART + 32768;  // segment capacity + slack
    int srcb = 1;
    while ((1 << srcb) < N) ++srcb;                    // 17 for N=100000

    char* w = (char*)d_ws;
    size_t off = 0;
    auto alloc = [&](size_t bytes) -> void* {
        void* p = w + off;
        off += (bytes + 255) & ~(size_t)255;
        return p;
    };
    int*      row_ptr  = (int*)alloc((size_t)(N + 1) * 4);
    int*      colarr   = (int*)alloc((size_t)E * 4);
    int*      partials = (int*)alloc(256 * 4);
    int*      cursor8  = (int*)alloc(8 * 4);
    float*    dinv     = (float*)alloc((size_t)N * 4);
    unsigned* h1f8     = (unsigned*)alloc((size_t)N * 32 * 4);  // fp8 X@W1 scaled (12.8MB)
    unsigned* h2b      = (unsigned*)alloc((size_t)N * 32 * 4);  // bf16 a1@W2 scaled (12.8MB)
    unsigned* Bp1      = (unsigned*)alloc(4 * 8 * 64 * 16);     // W1 frag stream 32KB
    unsigned* Bp2      = (unsigned*)alloc(4 * 4 * 64 * 16);     // W2 frag stream 16KB
    // pairs (7.5 MB) + cntarr (12.8 MB) alias h1f8+h2b (25.6 MB contiguous);
    // both are dead before k_gemm128_mfma writes h1f8.
    unsigned* pairsU   = (unsigned*)h1f8;
    int*      cntarr   = (int*)((char*)h1f8 + (size_t)NPART * capE * 4);
    (void)ws_size; (void)n_in; (void)out_size;

    int nscan = (N + 1023) / 1024;
    int nbb = (E + EB - 1) / EB;       // 782 bucket blocks
    int ngemm = (N + 63) / 64;
    int nagg = (N + 31) / 32;

    k_packW2<<<2, 256, 0, stream>>>(W1, Bp1, W2, Bp2, cursor8, partials);
    k_bucket_ballot<<<nbb, 256, 0, stream>>>(src, dst, cursor8, pairsU,
                                             E, npp, capE, srcb);
    k_count_part<<<NPART * KB, 256, 0, stream>>>(pairsU, cursor8, cntarr,
                                                 npp, capE, srcb);
    k_indeg_scan<<<nscan, 256, 0, stream>>>(cntarr, dinv, row_ptr, partials, N, npp);
    k_finalize_bases<<<(N + 255) / 256, 256, 0, stream>>>(row_ptr, partials, cntarr,
                                                          N, E, npp);
    k_fill2<<<NPART * KB, 256, 0, stream>>>(pairsU, cursor8, cntarr, colarr,
                                            npp, capE, srcb);

    k_gemm128_mfma<<<ngemm, 256, 0, stream>>>(x, Bp1, dinv, (unsigned char*)h1f8, N);
    k_agg_relu_gemm<<<nagg, 256, 0, stream>>>(h1f8, dinv, row_ptr, colarr,
                                              b1, Bp2, (unsigned short*)h2b, N);
    k_agg_lsm<<<nagg, 256, 0, stream>>>(h2b, dinv, row_ptr, colarr, b2, out, N);
}

// Round 12
// 252.271 us; speedup vs baseline: 1.0002x; 1.0002x over previous
//
#include <hip/hip_runtime.h>
#include <hip/hip_fp16.h>
#include <cstdint>
#include <cstddef>
#include <cstring>

// ---------------- bf16 pack/unpack helpers (RNE) ----------------

__device__ inline unsigned pack_bf16x2(float a, float b) {
    unsigned ua = __float_as_uint(a);
    unsigned ub = __float_as_uint(b);
    ua += 0x7fffu + ((ua >> 16) & 1u);
    ub += 0x7fffu + ((ub >> 16) & 1u);
    return (ua >> 16) | (ub & 0xffff0000u);
}
__device__ inline unsigned short bf16_rne(float v) {
    unsigned u = __float_as_uint(v);
    u += 0x7fffu + ((u >> 16) & 1u);
    return (unsigned short)(u >> 16);
}

// ---------------- fp8 (OCP e4m3fn) pack/unpack ----------------

typedef float fv2 __attribute__((ext_vector_type(2)));

template <bool HI>
__device__ inline fv2 fp8_fv2(unsigned u) {
#if __has_builtin(__builtin_amdgcn_cvt_pk_f32_fp8)
    return __builtin_amdgcn_cvt_pk_f32_fp8((int)u, HI);
#else
    unsigned u2 = HI ? (u >> 16) : (u & 0xffffu);
    unsigned w = (u2 & 0xFFu) | ((u2 & 0xFF00u) << 8);
    unsigned hb = ((w & 0x00800080u) << 8) | ((w & 0x007f007fu) << 7);
    __half2 h2;
    memcpy(&h2, &hb, 4);
    float2 f = __half22float2(h2);
    fv2 r;
    r.x = f.x * 256.0f;
    r.y = f.y * 256.0f;
    return r;
#endif
}

// bf16 pair (packed in a uint) -> fv2  (2 bitops, then packed add on use)
__device__ inline fv2 bfpair(unsigned u) {
    union { unsigned q[2]; fv2 f; } t;
    t.q[0] = u << 16;
    t.q[1] = u & 0xffff0000u;
    return t.f;
}

__device__ inline unsigned f32_to_fp8_byte(float v) {
    unsigned short hb = __half_as_ushort(__float2half(v * 0.00390625f));  // v/256
    unsigned t = hb & 0x7fffu;
    t += 0x3fu + ((t >> 7) & 1u);
    return ((hb >> 8) & 0x80u) | (t >> 7);
}

__device__ inline unsigned char f32_to_fp8_b(float v) {
#if __has_builtin(__builtin_amdgcn_cvt_pk_fp8_f32)
    return (unsigned char)(__builtin_amdgcn_cvt_pk_fp8_f32(v, v, 0, false) & 0xff);
#else
    return (unsigned char)f32_to_fp8_byte(v);
#endif
}

typedef int iv4 __attribute__((ext_vector_type(4)));

#define NPART 8
#define KB    32
#define NPP_MAX 12500
#define EB    2048   // edges per bucket block (8 per thread)
#define COLCAP 1536  // per-block LDS col-index cache (16 nodes, deg avg 16)

// ---------------- CSR build (R6-proven chain, R10-frozen) --------
// R7 lesson: mega-fusion pinned all phases at 1 block/CU -> 2x slower. Keep
// the chain; each phase runs at its own occupancy. Boundaries ~1us each.
//  - R3: col scatter-writes confined to L2-sized windows (no amplification)
//  - R5: never issue per-edge global atomics (coherence-point traffic)
//  - R6: ballot bucket -- zero per-edge atomics, 8 global atomics per block
//  - R10: finalize preloads slice counts into registers; scan folded in.
// R12: REVERT of R11's octet-gather experiment (252.3 vs 250.8 -- falsifier
// fired: agg kernels are gather/unpack-stream-bound, not MLP-bound).

__global__ __launch_bounds__(256) void k_bucket_ballot(const int* __restrict__ src,
                                                       const int* __restrict__ dst,
                                                       int* __restrict__ cursor8,
                                                       unsigned* __restrict__ pairs,
                                                       int E, int npp, int capE,
                                                       int srcb) {
    __shared__ int sWcnt[4][NPART];
    __shared__ int sWoff[4][NPART];
    int tid = threadIdx.x;
    int wv = tid >> 6;
    int lane = tid & 63;
    int base_e = blockIdx.x * EB + tid * 8;
    int nv = min(8, E - base_e);
    if (nv < 0) nv = 0;
    int dv[8], sv[8];
    if (nv == 8) {
        *(iv4*)(dv + 0) = *(const iv4*)(dst + base_e + 0);
        *(iv4*)(dv + 4) = *(const iv4*)(dst + base_e + 4);
        *(iv4*)(sv + 0) = *(const iv4*)(src + base_e + 0);
        *(iv4*)(sv + 4) = *(const iv4*)(src + base_e + 4);
    } else {
        for (int k = 0; k < 8; ++k) {
            dv[k] = (k < nv) ? dst[base_e + k] : -1;
            sv[k] = (k < nv) ? src[base_e + k] : 0;
        }
    }
    unsigned long long below = (1ull << lane) - 1ull;
    int wb[NPART];
#pragma unroll
    for (int pp = 0; pp < NPART; ++pp) wb[pp] = 0;
    int pv[8], pos[8];
#pragma unroll
    for (int s = 0; s < 8; ++s) {
        int d = dv[s];
        int p = (d >= 0) ? (int)((unsigned)d / (unsigned)npp) : NPART;
        pv[s] = p;
        unsigned long long msel = 0;
        int base = 0;
#pragma unroll
        for (int pp = 0; pp < NPART; ++pp) {
            unsigned long long m = __ballot(p == pp);
            if (p == pp) { msel = m; base = wb[pp]; }
            wb[pp] += (int)__popcll(m);   // ballot result is wave-uniform
        }
        pos[s] = base + (int)__popcll(msel & below);
    }
    // wave totals -> LDS (static indexing to keep wb in registers)
    if (lane < NPART) {
        int v = 0;
#pragma unroll
        for (int pp = 0; pp < NPART; ++pp)
            if (lane == pp) v = wb[pp];
        sWcnt[wv][lane] = v;
    }
    __syncthreads();
    if (tid < NPART) {
        int c0 = sWcnt[0][tid], c1 = sWcnt[1][tid], c2 = sWcnt[2][tid], c3 = sWcnt[3][tid];
        int gb = atomicAdd(&cursor8[tid], c0 + c1 + c2 + c3);  // 8 atomics/block
        sWoff[0][tid] = gb;
        sWoff[1][tid] = gb + c0;
        sWoff[2][tid] = gb + c0 + c1;
        sWoff[3][tid] = gb + c0 + c1 + c2;
    }
    __syncthreads();
#pragma unroll
    for (int s = 0; s < 8; ++s) {
        int p = pv[s];
        if (p < NPART) {
            int off = sWoff[wv][p];
            pairs[(size_t)p * capE + off + pos[s]] =
                ((unsigned)(dv[s] - p * npp) << srcb) | (unsigned)sv[s];
        }
    }
}

__global__ __launch_bounds__(256) void k_count_part(const unsigned* __restrict__ pairs,
                                                    const int* __restrict__ cursor8,
                                                    int* __restrict__ cntarr,
                                                    int npp, int capE, int srcb) {
    __shared__ int h[NPP_MAX];
    int p = blockIdx.x & (NPART - 1);
    int b = blockIdx.x >> 3;
    for (int i = threadIdx.x; i < npp; i += 256) h[i] = 0;
    __syncthreads();
    int sz = cursor8[p];
    int chunk = (sz + KB - 1) / KB;
    int s0 = b * chunk;
    int s1 = min(sz, s0 + chunk);
    const unsigned* seg = pairs + (size_t)p * capE;
    for (int i = s0 + threadIdx.x; i < s1; i += 256)
        atomicAdd(&h[seg[i] >> srcb], 1);
    __syncthreads();
    size_t out = (size_t)(p * KB + b) * npp;
    for (int i = threadIdx.x; i < npp; i += 256) cntarr[out + i] = h[i];
}

// Fused: per-node degree (sum of 32 cntarr slices) -> dinv + block-local scan.
__global__ void k_indeg_scan(const int* __restrict__ cntarr,
                             float* __restrict__ dinv,
                             int* __restrict__ row_ptr,
                             int* __restrict__ partials, int n, int npp) {
    __shared__ int s[256];
    int t = threadIdx.x;
    int node0 = blockIdx.x * 1024 + t * 4;
    int v0 = 0, v1 = 0, v2 = 0, v3 = 0;
    if (((npp & 3) == 0) && (node0 + 3 < n) && (node0 / npp == (node0 + 3) / npp)) {
        int p = node0 / npp;
        int dl = node0 - p * npp;
        size_t base = (size_t)p * KB * npp + dl;
        for (int b = 0; b < KB; ++b) {
            iv4 c = *(const iv4*)(cntarr + base + (size_t)b * npp);
            v0 += c.x; v1 += c.y; v2 += c.z; v3 += c.w;
        }
    } else {
        for (int r = 0; r < 4; ++r) {
            int node = node0 + r;
            if (node < n) {
                int p = node / npp;
                int dl = node - p * npp;
                size_t base = (size_t)p * KB * npp + dl;
                int sum = 0;
                for (int b = 0; b < KB; ++b) sum += cntarr[base + (size_t)b * npp];
                if (r == 0) v0 = sum; else if (r == 1) v1 = sum;
                else if (r == 2) v2 = sum; else v3 = sum;
            }
        }
    }
    if (node0 + 0 < n) dinv[node0 + 0] = rsqrtf((float)v0 + 1.0f);
    if (node0 + 1 < n) dinv[node0 + 1] = rsqrtf((float)v1 + 1.0f);
    if (node0 + 2 < n) dinv[node0 + 2] = rsqrtf((float)v2 + 1.0f);
    if (node0 + 3 < n) dinv[node0 + 3] = rsqrtf((float)v3 + 1.0f);
    int sum = v0 + v1 + v2 + v3;
    s[t] = sum;
    __syncthreads();
    for (int off = 1; off < 256; off <<= 1) {
        int x = (t >= off) ? s[t - off] : 0;
        __syncthreads();
        s[t] += x;
        __syncthreads();
    }
    int excl = s[t] - sum;
    if ((node0 + 0) < n) row_ptr[node0 + 0] = excl;
    if ((node0 + 1) < n) row_ptr[node0 + 1] = excl + v0;
    if ((node0 + 2) < n) row_ptr[node0 + 2] = excl + v0 + v1;
    if ((node0 + 3) < n) row_ptr[node0 + 3] = excl + v0 + v1 + v2;
    if (t == 255) partials[blockIdx.x] = s[255];
}

// Fused (R10): redundant in-block scan of partials + row_ptr fixup +
// per-slice base rewrite with REGISTER-PRELOADED counts.
__global__ void k_finalize_bases(int* __restrict__ row_ptr,
                                 const int* __restrict__ partials,
                                 int* __restrict__ cntarr, int n, int E, int npp) {
    __shared__ int s[256];
    int t = threadIdx.x;
    {   // redundant exclusive scan of partials[0..255] (zero-padded past nscan)
        int v = partials[t];
        s[t] = v;
        __syncthreads();
        for (int off = 1; off < 256; off <<= 1) {
            int x = (t >= off) ? s[t - off] : 0;
            __syncthreads();
            s[t] += x;
            __syncthreads();
        }
        int excl = s[t] - v;
        __syncthreads();
        s[t] = excl;
        __syncthreads();
    }
    int i = blockIdx.x * 256 + t;
    if (i >= n) return;
    int rp = row_ptr[i] + s[i >> 10];
    row_ptr[i] = rp;
    if (i == 0) row_ptr[n] = E;
    int p = (unsigned)i / (unsigned)npp;
    int dl = i - p * npp;
    size_t base = (size_t)p * KB * npp + dl;
    int c[KB];
#pragma unroll
    for (int b = 0; b < KB; ++b) c[b] = cntarr[base + (size_t)b * npp];
    int run = rp;
#pragma unroll
    for (int b = 0; b < KB; ++b) {
        cntarr[base + (size_t)b * npp] = run;
        run += c[b];
    }
}

__global__ __launch_bounds__(256) void k_fill2(const unsigned* __restrict__ pairs,
                                               const int* __restrict__ cursor8,
                                               const int* __restrict__ cntarr,
                                               int* __restrict__ col,
                                               int npp, int capE, int srcb) {
    __shared__ int cur[NPP_MAX];
    int p = blockIdx.x & (NPART - 1);
    int b = blockIdx.x >> 3;
    size_t slice = (size_t)(p * KB + b) * npp;
    for (int i = threadIdx.x; i < npp; i += 256) cur[i] = cntarr[slice + i];
    __syncthreads();
    int sz = cursor8[p];
    int chunk = (sz + KB - 1) / KB;
    int s0 = b * chunk;
    int s1 = min(sz, s0 + chunk);
    const unsigned* seg = pairs + (size_t)p * capE;
    unsigned smask = (1u << srcb) - 1u;
    for (int i = s0 + threadIdx.x; i < s1; i += 256) {
        unsigned u = seg[i];
        int pos = atomicAdd(&cur[u >> srcb], 1);
        col[pos] = (int)(u & smask);
    }
}

// ---------------- MFMA GEMMs ----------------
typedef __attribute__((ext_vector_type(8))) short short8;
typedef __attribute__((ext_vector_type(4))) float f32x4;

union FragU {
    short8 s;
    uint4 u4;
    unsigned u[4];
};

__device__ inline void packW_body(const float* __restrict__ W, unsigned* __restrict__ Bp,
                                  int NOUT, int NT) {
    int nf = 4 * NT * 64;
    for (int fid = threadIdx.x; fid < nf; fid += 256) {
        int q = fid / (NT * 64);
        int rem = fid - q * NT * 64;
        int nt = rem >> 6;
        int lane = rem & 63;
        int k0 = q * 32 + (lane >> 4) * 8;
        int ncol = nt * 16 + (lane & 15);
        unsigned u[4];
        for (int h = 0; h < 4; ++h) {
            float a = W[(k0 + 2 * h) * NOUT + ncol];
            float b = W[(k0 + 2 * h + 1) * NOUT + ncol];
            u[h] = pack_bf16x2(a, b);
        }
        uint4 o = {u[0], u[1], u[2], u[3]};
        *(uint4*)(Bp + (size_t)fid * 4) = o;
    }
}

// both weight packs in one dispatch; block 0 also zeroes cursor8 + partials
__global__ void k_packW2(const float* __restrict__ W1, unsigned* __restrict__ Bp1,
                         const float* __restrict__ W2, unsigned* __restrict__ Bp2,
                         int* __restrict__ cursor8, int* __restrict__ partials) {
    if (blockIdx.x == 0) {
        if (threadIdx.x < 8) cursor8[threadIdx.x] = 0;
        partials[threadIdx.x] = 0;
        packW_body(W1, Bp1, 128, 8);
    } else {
        packW_body(W2, Bp2, 64, 4);
    }
}

__global__ __launch_bounds__(256) void k_gemm128_mfma(const float* __restrict__ X,
                                                      const unsigned* __restrict__ Bp,
                                                      const float* __restrict__ dinv,
                                                      unsigned char* __restrict__ H8,
                                                      int n) {
    int w = threadIdx.x >> 6;
    int lane = threadIdx.x & 63;
    int quad = lane >> 4;
    int lrow = lane & 15;
    int row0 = blockIdx.x * 64 + w * 16;
    int rowA = min(row0 + lrow, n - 1);

    f32x4 acc[8];
    for (int nt = 0; nt < 8; ++nt) acc[nt] = (f32x4){0.f, 0.f, 0.f, 0.f};

    for (int q = 0; q < 4; ++q) {
        const float* xp = X + (size_t)rowA * 128 + q * 32 + quad * 8;
        float4 x0 = *(const float4*)xp;
        float4 x1 = *(const float4*)(xp + 4);
        FragU a;
        a.u[0] = pack_bf16x2(x0.x, x0.y);
        a.u[1] = pack_bf16x2(x0.z, x0.w);
        a.u[2] = pack_bf16x2(x1.x, x1.y);
        a.u[3] = pack_bf16x2(x1.z, x1.w);
        for (int nt = 0; nt < 8; ++nt) {
            FragU b;
            b.u4 = *(const uint4*)(Bp + ((size_t)(q * 8 + nt) * 64 + lane) * 4);
            acc[nt] = __builtin_amdgcn_mfma_f32_16x16x32_bf16(a.s, b.s, acc[nt], 0, 0, 0);
        }
    }

    int rbase = row0 + quad * 4;
    float dv[4];
    if (rbase + 3 < n) {
        float4 d4 = *(const float4*)(dinv + rbase);
        dv[0] = d4.x; dv[1] = d4.y; dv[2] = d4.z; dv[3] = d4.w;
    } else {
        for (int r = 0; r < 4; ++r) dv[r] = dinv[min(rbase + r, n - 1)];
    }
    for (int nt = 0; nt < 8; ++nt) {
        for (int r = 0; r < 4; ++r) {
            int row = rbase + r;
            if (row < n)
                H8[(size_t)row * 128 + nt * 16 + lrow] = f32_to_fp8_b(dv[r] * acc[nt][r]);
        }
    }
}

// ---------------- Layer-1 aggregation FUSED with the W2 GEMM ----------------
// R13-proven agg structure (quarter-wave per node). R9: the block's 16 nodes
// are consecutive, so their CSR col entries are ONE contiguous range --
// stage it into LDS once (coalesced), then the gather loop reads indices via
// LDS broadcast instead of a serialized global round-trip per 8-edge batch.
// Quarter-uniform fallback to global col for pathological blocks (>COLCAP).
#define ACC8(u) \
    a0 += fp8_fv2<false>((u).x); a1 += fp8_fv2<true>((u).x); \
    a2 += fp8_fv2<false>((u).y); a3 += fp8_fv2<true>((u).y);

__global__ __launch_bounds__(256) void k_agg_relu_gemm(const unsigned* __restrict__ hs,
                                                       const float* __restrict__ dinv,
                                                       const int* __restrict__ row_ptr,
                                                       const int* __restrict__ col,
                                                       const float* __restrict__ bias,
                                                       const unsigned* __restrict__ Bp2,
                                                       unsigned short* __restrict__ H16,
                                                       int n) {
    __shared__ unsigned s_a[16][68];
    __shared__ int s_rp[17];
    __shared__ int s_col[COLCAP];
    int tid = threadIdx.x;
    int q16 = tid >> 4;                 // local node 0..15
    int node0 = blockIdx.x * 16;
    int node = node0 + q16;
    int l = tid & 15;
    bool alive = node < n;
    int nodeC = alive ? node : (n - 1);
    if (tid < 17) s_rp[tid] = row_ptr[min(node0 + tid, n)];
    __syncthreads();
    int base = s_rp[0];
    int total = s_rp[16] - base;
    int nld = min(total, COLCAP);
    for (int i = tid; i < nld; i += 256) s_col[i] = col[base + i];
    __syncthreads();

    const uint2* hrow = (const uint2*)hs;
    fv2 a0 = {0.f, 0.f}, a1 = {0.f, 0.f}, a2 = {0.f, 0.f}, a3 = {0.f, 0.f};
    if (alive) {   // self term
        uint2 u = hrow[(size_t)node * 16 + l];
        ACC8(u)
    }
    int kk = s_rp[q16] - base;
    int kend = s_rp[q16 + 1] - base;
    if (kend <= COLCAP) {   // fast path: indices from LDS (broadcast reads)
        for (; kk + 8 <= kend; kk += 8) {
            int cA = s_col[kk + 0], cB = s_col[kk + 1], cC = s_col[kk + 2], cD = s_col[kk + 3];
            int cE = s_col[kk + 4], cF = s_col[kk + 5], cG = s_col[kk + 6], cH = s_col[kk + 7];
            uint2 uA = hrow[(size_t)cA * 16 + l];
            uint2 uB = hrow[(size_t)cB * 16 + l];
            uint2 uC = hrow[(size_t)cC * 16 + l];
            uint2 uD = hrow[(size_t)cD * 16 + l];
            uint2 uE = hrow[(size_t)cE * 16 + l];
            uint2 uF = hrow[(size_t)cF * 16 + l];
            uint2 uG = hrow[(size_t)cG * 16 + l];
            uint2 uH = hrow[(size_t)cH * 16 + l];
            ACC8(uA) ACC8(uB) ACC8(uC) ACC8(uD)
            ACC8(uE) ACC8(uF) ACC8(uG) ACC8(uH)
        }
        for (; kk + 4 <= kend; kk += 4) {
            int cA = s_col[kk + 0], cB = s_col[kk + 1], cC = s_col[kk + 2], cD = s_col[kk + 3];
            uint2 uA = hrow[(size_t)cA * 16 + l];
            uint2 uB = hrow[(size_t)cB * 16 + l];
            uint2 uC = hrow[(size_t)cC * 16 + l];
            uint2 uD = hrow[(size_t)cD * 16 + l];
            ACC8(uA) ACC8(uB) ACC8(uC) ACC8(uD)
        }
        for (; kk < kend; ++kk) {
            uint2 u = hrow[(size_t)s_col[kk] * 16 + l];
            ACC8(u)
        }
    } else {                 // rare fallback: global col
        const int* cp = col + base;
        for (; kk + 4 <= kend; kk += 4) {
            int cA = cp[kk + 0], cB = cp[kk + 1], cC = cp[kk + 2], cD = cp[kk + 3];
            uint2 uA = hrow[(size_t)cA * 16 + l];
            uint2 uB = hrow[(size_t)cB * 16 + l];
            uint2 uC = hrow[(size_t)cC * 16 + l];
            uint2 uD = hrow[(size_t)cD * 16 + l];
            ACC8(uA) ACC8(uB) ACC8(uC) ACC8(uD)
        }
        for (; kk < kend; ++kk) {
            uint2 u = hrow[(size_t)cp[kk] * 16 + l];
            ACC8(u)
        }
    }
    // epilogue: every lane finalizes its own 8 columns -> bf16 into LDS tile
    {
        float di = dinv[nodeC];
        float4 b4a = *(const float4*)(bias + 8 * l);
        float4 b4b = *(const float4*)(bias + 8 * l + 4);
        float v0 = fmaf(di, a0.x, b4a.x);
        float v1 = fmaf(di, a0.y, b4a.y);
        float v2 = fmaf(di, a1.x, b4a.z);
        float v3 = fmaf(di, a1.y, b4a.w);
        float v4 = fmaf(di, a2.x, b4b.x);
        float v5 = fmaf(di, a2.y, b4b.y);
        float v6 = fmaf(di, a3.x, b4b.z);
        float v7 = fmaf(di, a3.y, b4b.w);
        v0 = v0 > 0.f ? v0 : 0.f;
        v1 = v1 > 0.f ? v1 : 0.f;
        v2 = v2 > 0.f ? v2 : 0.f;
        v3 = v3 > 0.f ? v3 : 0.f;
        v4 = v4 > 0.f ? v4 : 0.f;
        v5 = v5 > 0.f ? v5 : 0.f;
        v6 = v6 > 0.f ? v6 : 0.f;
        v7 = v7 > 0.f ? v7 : 0.f;
        uint4 o = {pack_bf16x2(v0, v1), pack_bf16x2(v2, v3),
                   pack_bf16x2(v4, v5), pack_bf16x2(v6, v7)};
        *(uint4*)&s_a[q16][4 * l] = o;
    }
    __syncthreads();
    // W2 GEMM: 16 nodes x 128 @ 128 x 64. Wave w owns N-tile nt=w (16 cols).
    // Fragment layouts identical to the standalone gemm64 (A: row=lane&15,
    // k-chunk=q*16+4*quad uints; C: row=quad*4+r, col=nt*16+(lane&15)).
    {
        int lane = threadIdx.x & 63;
        int w = threadIdx.x >> 6;
        int quad = lane >> 4;
        int lrow = lane & 15;
        f32x4 acc = (f32x4){0.f, 0.f, 0.f, 0.f};
        for (int q = 0; q < 4; ++q) {
            FragU a, b;
            a.u4 = *(const uint4*)&s_a[lrow][16 * q + 4 * quad];
            b.u4 = *(const uint4*)(Bp2 + ((size_t)(q * 4 + w) * 64 + lane) * 4);
            acc = __builtin_amdgcn_mfma_f32_16x16x32_bf16(a.s, b.s, acc, 0, 0, 0);
        }
        int rbase = blockIdx.x * 16 + quad * 4;
        for (int r = 0; r < 4; ++r) {
            int nd = rbase + r;
            if (nd < n)
                H16[(size_t)nd * 64 + w * 16 + lrow] = bf16_rne(dinv[nd] * acc[r]);
        }
    }
}

// Layer 2: hs rows = 16 uint2 (64 bf16). Lane owns bf16 cols 4l..4l+3.
// Same LDS col-index staging; fused log_softmax (16-lane quarter reduce).
#define ACCL(u) \
    aX += bfpair((u).x); aY += bfpair((u).y);

__global__ __launch_bounds__(256) void k_agg_lsm(const unsigned* __restrict__ hs,
                                                 const float* __restrict__ dinv,
                                                 const int* __restrict__ row_ptr,
                                                 const int* __restrict__ col,
                                                 const float* __restrict__ bias,
                                                 float* __restrict__ out, int n) {
    __shared__ int s_rp[17];
    __shared__ int s_col[COLCAP];
    int tid = threadIdx.x;
    int q16 = tid >> 4;
    int node0 = blockIdx.x * 16;
    int node = node0 + q16;
    int l = tid & 15;
    bool alive = node < n;
    int nodeC = alive ? node : (n - 1);
    if (tid < 17) s_rp[tid] = row_ptr[min(node0 + tid, n)];
    __syncthreads();
    int base = s_rp[0];
    int total = s_rp[16] - base;
    int nld = min(total, COLCAP);
    for (int i = tid; i < nld; i += 256) s_col[i] = col[base + i];
    __syncthreads();

    const uint2* hrow = (const uint2*)hs;
    fv2 aX = {0.f, 0.f}, aY = {0.f, 0.f};
    if (alive) {   // self term
        uint2 u = hrow[(size_t)node * 16 + l];
        ACCL(u)
    }
    int kk = s_rp[q16] - base;
    int kend = s_rp[q16 + 1] - base;
    if (kend <= COLCAP) {
        for (; kk + 8 <= kend; kk += 8) {
            int cA = s_col[kk + 0], cB = s_col[kk + 1], cC = s_col[kk + 2], cD = s_col[kk + 3];
            int cE = s_col[kk + 4], cF = s_col[kk + 5], cG = s_col[kk + 6], cH = s_col[kk + 7];
            uint2 uA = hrow[(size_t)cA * 16 + l];
            uint2 uB = hrow[(size_t)cB * 16 + l];
            uint2 uC = hrow[(size_t)cC * 16 + l];
            uint2 uD = hrow[(size_t)cD * 16 + l];
            uint2 uE = hrow[(size_t)cE * 16 + l];
            uint2 uF = hrow[(size_t)cF * 16 + l];
            uint2 uG = hrow[(size_t)cG * 16 + l];
            uint2 uH = hrow[(size_t)cH * 16 + l];
            ACCL(uA) ACCL(uB) ACCL(uC) ACCL(uD)
            ACCL(uE) ACCL(uF) ACCL(uG) ACCL(uH)
        }
        for (; kk + 4 <= kend; kk += 4) {
            int cA = s_col[kk + 0], cB = s_col[kk + 1], cC = s_col[kk + 2], cD = s_col[kk + 3];
            uint2 uA = hrow[(size_t)cA * 16 + l];
            uint2 uB = hrow[(size_t)cB * 16 + l];
            uint2 uC = hrow[(size_t)cC * 16 + l];
            uint2 uD = hrow[(size_t)cD * 16 + l];
            ACCL(uA) ACCL(uB) ACCL(uC) ACCL(uD)
        }
        for (; kk < kend; ++kk) {
            uint2 u = hrow[(size_t)s_col[kk] * 16 + l];
            ACCL(u)
        }
    } else {
        const int* cp = col + base;
        for (; kk + 4 <= kend; kk += 4) {
            int cA = cp[kk + 0], cB = cp[kk + 1], cC = cp[kk + 2], cD = cp[kk + 3];
            uint2 uA = hrow[(size_t)cA * 16 + l];
            uint2 uB = hrow[(size_t)cB * 16 + l];
            uint2 uC = hrow[(size_t)cC * 16 + l];
            uint2 uD = hrow[(size_t)cD * 16 + l];
            ACCL(uA) ACCL(uB) ACCL(uC) ACCL(uD)
        }
        for (; kk < kend; ++kk) {
            uint2 u = hrow[(size_t)cp[kk] * 16 + l];
            ACCL(u)
        }
    }
    float di = dinv[nodeC];
    float4 b4 = *(const float4*)(bias + 4 * l);
    float v0 = fmaf(di, aX.x, b4.x);
    float v1 = fmaf(di, aX.y, b4.y);
    float v2 = fmaf(di, aY.x, b4.z);
    float v3 = fmaf(di, aY.y, b4.w);
    float m = fmaxf(fmaxf(v0, v1), fmaxf(v2, v3));
    for (int off = 8; off; off >>= 1) m = fmaxf(m, __shfl_xor(m, off));
    float s = __expf(v0 - m) + __expf(v1 - m) + __expf(v2 - m) + __expf(v3 - m);
    for (int off = 8; off; off >>= 1) s += __shfl_xor(s, off);
    float ls = __logf(s);
    if (alive) {
        float4 o = {v0 - m - ls, v1 - m - ls, v2 - m - ls, v3 - m - ls};
        *(float4*)(out + (size_t)node * 64 + 4 * l) = o;
    }
}

// ---------------- launcher ----------------

extern "C" void kernel_launch(void* const* d_in, const int* in_sizes, int n_in,
                              void* d_out, int out_size, void* d_ws, size_t ws_size,
                              hipStream_t stream) {
    const float* x  = (const float*)d_in[0];
    const int*   ei = (const int*)d_in[1];
    const float* W1 = (const float*)d_in[2];
    const float* b1 = (const float*)d_in[3];
    const float* W2 = (const float*)d_in[4];
    const float* b2 = (const float*)d_in[5];
    float* out = (float*)d_out;

    const int N = in_sizes[0] / 128;   // 100000
    const int E = in_sizes[1] / 2;     // 1600000
    const int* src = ei;
    const int* dst = ei + E;
    const int npp = (N + NPART - 1) / NPART;           // 12500
    const int capE = (E + NPART - 1) / NPART + 32768;  // segment capacity + slack
    int srcb = 1;
    while ((1 << srcb) < N) ++srcb;                    // 17 for N=100000

    char* w = (char*)d_ws;
    size_t off = 0;
    auto alloc = [&](size_t bytes) -> void* {
        void* p = w + off;
        off += (bytes + 255) & ~(size_t)255;
        return p;
    };
    int*      row_ptr  = (int*)alloc((size_t)(N + 1) * 4);
    int*      colarr   = (int*)alloc((size_t)E * 4);
    int*      partials = (int*)alloc(256 * 4);
    int*      cursor8  = (int*)alloc(8 * 4);
    float*    dinv     = (float*)alloc((size_t)N * 4);
    unsigned* h1f8     = (unsigned*)alloc((size_t)N * 32 * 4);  // fp8 X@W1 scaled (12.8MB)
    unsigned* h2b      = (unsigned*)alloc((size_t)N * 32 * 4);  // bf16 a1@W2 scaled (12.8MB)
    unsigned* Bp1      = (unsigned*)alloc(4 * 8 * 64 * 16);     // W1 frag stream 32KB
    unsigned* Bp2      = (unsigned*)alloc(4 * 4 * 64 * 16);     // W2 frag stream 16KB
    // pairs (7.5 MB) + cntarr (12.8 MB) alias h1f8+h2b (25.6 MB contiguous);
    // both are dead before k_gemm128_mfma writes h1f8.
    unsigned* pairsU   = (unsigned*)h1f8;
    int*      cntarr   = (int*)((char*)h1f8 + (size_t)NPART * capE * 4);
    (void)ws_size; (void)n_in; (void)out_size;

    int nscan = (N + 1023) / 1024;
    int nbb = (E + EB - 1) / EB;       // 782 bucket blocks
    int ngemm = (N + 63) / 64;

    k_packW2<<<2, 256, 0, stream>>>(W1, Bp1, W2, Bp2, cursor8, partials);
    k_bucket_ballot<<<nbb, 256, 0, stream>>>(src, dst, cursor8, pairsU,
                                             E, npp, capE, srcb);
    k_count_part<<<NPART * KB, 256, 0, stream>>>(pairsU, cursor8, cntarr,
                                                 npp, capE, srcb);
    k_indeg_scan<<<nscan, 256, 0, stream>>>(cntarr, dinv, row_ptr, partials, N, npp);
    k_finalize_bases<<<(N + 255) / 256, 256, 0, stream>>>(row_ptr, partials, cntarr,
                                                          N, E, npp);
    k_fill2<<<NPART * KB, 256, 0, stream>>>(pairsU, cursor8, cntarr, colarr,
                                            npp, capE, srcb);

    k_gemm128_mfma<<<ngemm, 256, 0, stream>>>(x, Bp1, dinv, (unsigned char*)h1f8, N);
    k_agg_relu_gemm<<<(N + 15) / 16, 256, 0, stream>>>(h1f8, dinv, row_ptr, colarr,
                                                       b1, Bp2, (unsigned short*)h2b, N);
    k_agg_lsm<<<(N + 15) / 16, 256, 0, stream>>>(h2b, dinv, row_ptr, colarr, b2, out, N);
}